// Round 5
// baseline (99.899 us; speedup 1.0000x reference)
//
#include <hip/hip_runtime.h>
#include <hip/hip_bf16.h>

#define NB 16
#define CI 512
#define CO 512
#define HW 1024
#define SD 512
#define EPSI 1e-8f

typedef __attribute__((ext_vector_type(8))) short bf16x8;
typedef __attribute__((ext_vector_type(16))) float f32x16;
typedef __attribute__((ext_vector_type(4))) unsigned int u32x4;

#define GLOAD_LDS16(g, l) __builtin_amdgcn_global_load_lds( \
    (const __attribute__((address_space(1))) unsigned int*)(const void*)(g), \
    (__attribute__((address_space(3))) unsigned int*)(void*)(l), 16, 0, 0)
#define SCHED0() __builtin_amdgcn_sched_barrier(0)
#define SBAR()   __builtin_amdgcn_s_barrier()

// ---- style[b][c] = dot(w[b,:], style_w[c,:]) + style_b[c]  (one wave per output)
__global__ void k_style2(const float* __restrict__ w, const float* __restrict__ sw,
                         const float* __restrict__ sb, float* __restrict__ style) {
    int gw = (blockIdx.x * 256 + threadIdx.x) >> 6;   // 0..8191
    int l = threadIdx.x & 63;
    int b = gw >> 9, c = gw & 511;
    const float4* wr = (const float4*)(w + b * SD) + (l << 1);
    const float4* sr = (const float4*)(sw + c * SD) + (l << 1);
    float4 a0 = wr[0], a1 = wr[1], q0 = sr[0], q1 = sr[1];
    float acc = a0.x * q0.x + a0.y * q0.y + a0.z * q0.z + a0.w * q0.w
              + a1.x * q1.x + a1.y * q1.y + a1.z * q1.z + a1.w * q1.w;
#pragma unroll
    for (int off = 32; off > 0; off >>= 1) acc += __shfl_down(acc, off);
    if (l == 0) style[gw] = acc + sb[c];
}

// ---- wsq[co][ci] = sum_t weight^2 ; write Wt[t][co][ci] bf16 ; zero the zpage
__global__ void k_wprep(const float* __restrict__ wt, float* __restrict__ wsq,
                        __hip_bfloat16* __restrict__ wtb, u32x4* __restrict__ zpage) {
    if (blockIdx.x == 0 && threadIdx.x < 64)
        zpage[threadIdx.x] = (u32x4){0, 0, 0, 0};
    int idx = blockIdx.x * 256 + threadIdx.x;       // co*512+ci
    const float* p = wt + idx * 9;
    float a = 0.f;
#pragma unroll
    for (int t = 0; t < 9; ++t) {
        float v = p[t];
        a += v * v;
        wtb[t * (CO * CI) + idx] = __float2bfloat16(v);
    }
    wsq[idx] = a;
}

// ---- d[b][co] = rsqrt(sum_ci style^2 * wsq + eps)  (one wave per output)
__global__ void k_demod2(const float* __restrict__ style, const float* __restrict__ wsq,
                         float* __restrict__ dv) {
    int gw = (blockIdx.x * 256 + threadIdx.x) >> 6;
    int l = threadIdx.x & 63;
    int b = gw >> 9, co = gw & 511;
    const float4* st = (const float4*)(style + b * CI) + (l << 1);
    const float4* wq = (const float4*)(wsq + co * CI) + (l << 1);
    float4 s0 = st[0], s1 = st[1], q0 = wq[0], q1 = wq[1];
    float acc = s0.x * s0.x * q0.x + s0.y * s0.y * q0.y + s0.z * s0.z * q0.z + s0.w * s0.w * q0.w
              + s1.x * s1.x * q1.x + s1.y * s1.y * q1.y + s1.z * s1.z * q1.z + s1.w * s1.w * q1.w;
#pragma unroll
    for (int off = 32; off > 0; off >>= 1) acc += __shfl_down(acc, off);
    if (l == 0) dv[gw] = rsqrtf(acc + EPSI);
}

// ---- xs[b][p][ci] = bf16(style[b][ci] * x[b][ci][p])   (transpose to ci-innermost)
__global__ void k_xs(const float* __restrict__ x, const float* __restrict__ style,
                     __hip_bfloat16* __restrict__ xs) {
    __shared__ float tile[32][33];
    int b = blockIdx.z, c0 = blockIdx.y * 32, p0 = blockIdx.x * 32;
    int tx = threadIdx.x & 31, ty = threadIdx.x >> 5;
#pragma unroll
    for (int i = 0; i < 4; ++i) {
        int ci = c0 + ty + i * 8;
        tile[ty + i * 8][tx] = x[(b * CI + ci) * HW + p0 + tx] * style[b * CI + ci];
    }
    __syncthreads();
#pragma unroll
    for (int i = 0; i < 4; ++i) {
        int p = p0 + ty + i * 8;
        xs[(b * HW + p) * CI + c0 + tx] = __float2bfloat16(tile[tx][ty + i * 8]);
    }
}

// ---- conv: 1 block = 128co x 128px x 1 batch; 4 waves, per-wave 64co x 64px (32x32x16)
// 2 blocks/CU (independent barrier domains) hide each other's stalls.
// X single buffer (26112 B) + W triple buffer (3x16384 B) = 75264 B/block.
#define XS_BYTES 26112
#define WBUF_BYTES 16384
#define SMEM_TOTAL (XS_BYTES + 3 * WBUF_BYTES)   // 75264

extern "C" __global__ __launch_bounds__(256, 2) void k_conv(
        const __hip_bfloat16* __restrict__ wtb,
        const __hip_bfloat16* __restrict__ xs,
        const float* __restrict__ dvec,
        const char* __restrict__ zpage,
        float* __restrict__ out) {
    extern __shared__ char smem[];
    char* Xs  = smem;                    // single buffer
    char* Wsb = smem + XS_BYTES;         // 3 buffers

    const int tid  = threadIdx.x;
    const int lane = tid & 63;
    const int wv   = tid >> 6;           // 0..3
    const int wr   = wv >> 1;            // co half (64)
    const int wn   = wv & 1;             // px half (64)

    // XCD swizzle: one co-panel per XCD pair (W panel L2-resident); batches split on xcd&1
    int bid = blockIdx.x;
    int xcd = bid & 7, idx = bid >> 3;   // idx 0..63
    const int cot = xcd >> 1;
    const int px8 = idx & 7;
    const int b   = (idx >> 3) | ((xcd & 1) << 3);
    const int co0 = cot * 128;
    const int p0  = px8 * 128;
    const int y0  = px8 * 4;

    // zero halo pad columns rx=0 and rx=33 (stay zero for whole kernel)
    if (tid < 96) {
        int g = tid & 7;
        int rx = (tid & 8) ? 33 : 0;
        int row = tid >> 4;              // 0..5
        *(u32x4*)(Xs + (row * 34 + rx) * 128 + g * 16) = (u32x4){0, 0, 0, 0};
    }

    const int srcgW = (lane & 7) ^ (lane >> 3);

    // W stage: 16 segments, 4 per wave. stage s -> buffer (s%9)%3
    auto issueW = [&](int tap, int cin, int bufi) {
        const __hip_bfloat16* wsrc = wtb + ((size_t)tap * CO + co0) * CI + cin;
        char* wdst = Wsb + bufi * WBUF_BYTES;
#pragma unroll
        for (int k = 0; k < 4; ++k) {
            int seg = k * 4 + wv;
            int co_l = seg * 8 + (lane >> 3);
            GLOAD_LDS16(wsrc + co_l * CI + srcgW * 8, wdst + seg * 1024);
        }
    };
    // X stage: 24 segments, 6 per wave; OOB rows stream zeros from zpage (uniform ledger)
    auto issueX = [&](int cin) {
#pragma unroll
        for (int k = 0; k < 6; ++k) {
            int sid = k * 4 + wv;
            int ry = sid >> 2, seg = sid & 3;
            int rx0 = 1 + seg * 8;
            char* ldst = Xs + (ry * 34 + rx0) * 128;
            int y = y0 - 1 + ry;
            int rx = rx0 + (lane >> 3);
            int srcg = (lane & 7) ^ (rx & 7);
            if ((unsigned)y < 32u)
                GLOAD_LDS16(xs + ((size_t)b * HW + (y << 5) + (rx - 1)) * CI + cin + srcg * 8, ldst);
            else
                GLOAD_LDS16(zpage, ldst);
        }
    };

    f32x16 acc[2][2];
#pragma unroll
    for (int m = 0; m < 2; ++m)
#pragma unroll
        for (int n = 0; n < 2; ++n)
            acc[m][n] = (f32x16)(0.f);

    // ---- prologue: W(0)->buf0, W(1)->buf1, X(0); full drain; barrier
    issueW(0, 0, 0);
    issueW(1, 0, 1);
    issueX(0);
    SCHED0();
    asm volatile("s_waitcnt lgkmcnt(0) vmcnt(0)" ::: "memory");
    SCHED0();
    SBAR();
    SCHED0();

    for (int cc = 0; cc < 8; ++cc) {
#pragma unroll
        for (int t = 0; t < 9; ++t) {
            // ---- post-barrier issue region: W(s+2) depth-2
            if (!(cc == 7 && t >= 7)) {
                const int tn  = (t <= 6) ? (t + 2) : (t - 7);
                const int cin = ((t <= 6) ? cc : (cc + 1)) * 64;
                issueW(tn, cin, (t + 2) % 3);
            }
            SCHED0();

            // ---- compute tap t from W buffer t%3
            const char* Wb = Wsb + (t % 3) * WBUF_BYTES;
            const int ky = t / 3, kx = t - (t / 3) * 3;
            __builtin_amdgcn_s_setprio(1);
#pragma unroll
            for (int q = 0; q < 4; ++q) {
                bf16x8 afr[2], bfr[2];
                int g = (q << 1) + (lane >> 5);
#pragma unroll
                for (int m = 0; m < 2; ++m) {
                    int cr = wr * 64 + m * 32 + (lane & 31);
                    afr[m] = *(const bf16x8*)(Wb + cr * 128 + ((g ^ (cr & 7)) << 4));
                }
#pragma unroll
                for (int n = 0; n < 2; ++n) {
                    int ry = wn * 2 + n + ky;
                    int rx = (lane & 31) + kx;
                    bfr[n] = *(const bf16x8*)(Xs + ((ry * 34 + rx) * 128) +
                                              ((g ^ (rx & 7)) << 4));
                }
#pragma unroll
                for (int m = 0; m < 2; ++m)
#pragma unroll
                    for (int n = 0; n < 2; ++n)
                        acc[m][n] = __builtin_amdgcn_mfma_f32_32x32x16_bf16(afr[m], bfr[n], acc[m][n], 0, 0, 0);
            }
            __builtin_amdgcn_s_setprio(0);

            // ---- end-of-tap sync
            if (cc == 7 && t == 8) {
                // last tap: fall through to epilogue
            } else if (t == 8) {
                // cc boundary: all waves done reading X -> barrier A, restage X, drain, barrier B
                SCHED0();
                asm volatile("s_waitcnt lgkmcnt(0)" ::: "memory");
                SCHED0();
                SBAR();
                SCHED0();
                issueX((cc + 1) * 64);
                SCHED0();
                asm volatile("s_waitcnt lgkmcnt(0) vmcnt(0)" ::: "memory");
                SCHED0();
                SBAR();
                SCHED0();
            } else if (cc == 7 && t == 7) {
                SCHED0();
                asm volatile("s_waitcnt lgkmcnt(0) vmcnt(0)" ::: "memory");
                SCHED0();
                SBAR();
                SCHED0();
            } else {
                SCHED0();
                asm volatile("s_waitcnt lgkmcnt(0) vmcnt(4)" ::: "memory");
                SCHED0();
                SBAR();
                SCHED0();
            }
        }
    }

    // epilogue: d-scale + store f32. 32x32 C layout: col=lane&31, row=(r&3)+8*(r>>2)+4*(lane>>5)
#pragma unroll
    for (int m = 0; m < 2; ++m) {
#pragma unroll
        for (int r = 0; r < 16; ++r) {
            int co = co0 + wr * 64 + m * 32 + (r & 3) + ((r >> 2) << 3) + ((lane >> 5) << 2);
            float dvv = dvec[b * CO + co];
            float* orow = out + ((size_t)b * CO + co) * HW + p0 + wn * 64;
            orow[lane & 31]        = acc[m][0][r] * dvv;
            orow[32 + (lane & 31)] = acc[m][1][r] * dvv;
        }
    }
}

extern "C" void kernel_launch(void* const* d_in, const int* in_sizes, int n_in,
                              void* d_out, int out_size, void* d_ws, size_t ws_size,
                              hipStream_t stream) {
    const float* x  = (const float*)d_in[0];
    const float* w  = (const float*)d_in[1];
    const float* sw = (const float*)d_in[2];
    const float* sb = (const float*)d_in[3];
    const float* wt = (const float*)d_in[4];
    float* out = (float*)d_out;

    char* ws = (char*)d_ws;
    float* style = (float*)(ws);                               // 32 KB
    float* dvec  = (float*)(ws + 32768);                       // 32 KB
    float* wsq   = (float*)(ws + 65536);                       // 1 MB
    __hip_bfloat16* wtb = (__hip_bfloat16*)(ws + 1114112);     // 4.72 MB
    __hip_bfloat16* xsb = (__hip_bfloat16*)(ws + 5832704);     // 16.78 MB
    char* zpage = ws + 22609920;                               // 1 KB zero page

    hipFuncSetAttribute((const void*)k_conv,
                        hipFuncAttributeMaxDynamicSharedMemorySize, SMEM_TOTAL);

    k_style2<<<2048, 256, 0, stream>>>(w, sw, sb, style);
    k_wprep<<<1024, 256, 0, stream>>>(wt, wsq, (__hip_bfloat16*)wtb, (u32x4*)zpage);
    k_xs<<<dim3(32, 16, 16), 256, 0, stream>>>(x, style, xsb);
    k_demod2<<<2048, 256, 0, stream>>>(style, wsq, dvec);
    k_conv<<<512, 256, SMEM_TOTAL, stream>>>(wtb, xsb, dvec, zpage, out);
}